// Round 12
// baseline (153.475 us; speedup 1.0000x reference)
//
#include <hip/hip_runtime.h>
#include <hip/hip_bf16.h>
#include <math.h>

#define IN_F 256
#define OUT_F 128
#define HEADS 4
#define HF 512    // HEADS*OUT_F
#define NCAT 1280 // 512 + 512 + 128 + 128

typedef __hip_bfloat16 bf16;
typedef unsigned short ushort_t;
typedef unsigned char uchar_t;

using bf16x8 = __attribute__((ext_vector_type(8))) short;
using f32x4  = __attribute__((ext_vector_type(4))) float;

__device__ __forceinline__ float bflo(unsigned u) { return __uint_as_float(u << 16); }
__device__ __forceinline__ float bfhi(unsigned u) { return __uint_as_float(u & 0xffff0000u); }
__device__ __forceinline__ float bf2f(ushort_t u) { return __uint_as_float((unsigned)u << 16); }
__device__ __forceinline__ ushort_t f2bf(float f) {
    __hip_bfloat16 h = __float2bfloat16(f);
    return *reinterpret_cast<ushort_t*>(&h);
}

// async global->LDS, 16B per lane; dest = wave-uniform base + lane*16
__device__ __forceinline__ void gload16(const void* g, void* l) {
    __builtin_amdgcn_global_load_lds(
        (const __attribute__((address_space(1))) unsigned int*)g,
        (__attribute__((address_space(3))) unsigned int*)l, 16, 0, 0);
}

// sum over 16-lane row via DPP row_ror (all lanes end with full sum)
template <int CTRL>
__device__ __forceinline__ float dpp_add(float s) {
    int t = __builtin_amdgcn_update_dpp(0, __float_as_int(s), CTRL, 0xf, 0xf, true);
    return s + __int_as_float(t);
}
__device__ __forceinline__ float rowsum16(float s) {
    s = dpp_add<0x121>(s);
    s = dpp_add<0x122>(s);
    s = dpp_add<0x124>(s);
    s = dpp_add<0x128>(s);
    return s;
}

// ---------------- fused prep: cvt_x | build weights | hist ----------------
__global__ __launch_bounds__(256) void prep_kernel(
    const float* __restrict__ x, ushort_t* __restrict__ xb, int n_cvt,
    const float* __restrict__ Wl, const float* __restrict__ Wr,
    const float* __restrict__ Wc, const float* __restrict__ Wres,
    const float* __restrict__ Wconv,
    ushort_t* __restrict__ Wt, ushort_t* __restrict__ Wt2,
    const int* __restrict__ ei, int* __restrict__ counts, int E,
    int g1, int g2) {
    int b = blockIdx.x;
    if (b < g1) {
        int i = (b * 256 + threadIdx.x) * 8;
        if (i >= n_cvt) return;
        float4 a = *(const float4*)(x + i);
        float4 c = *(const float4*)(x + i + 4);
        uint4 o;
        o.x = f2bf(a.x) | ((unsigned)f2bf(a.y) << 16);
        o.y = f2bf(a.z) | ((unsigned)f2bf(a.w) << 16);
        o.z = f2bf(c.x) | ((unsigned)f2bf(c.y) << 16);
        o.w = f2bf(c.z) | ((unsigned)f2bf(c.w) << 16);
        *(uint4*)(xb + i) = o;
    } else if (b < g2) {
        int idx = (b - g1) * 256 + threadIdx.x;
        if (idx < NCAT * 256) {
            int n = idx >> 8, k = idx & 255;
            float v;
            if (n < 512)       v = Wl[(size_t)k * 512 + n];
            else if (n < 1024) v = Wr[(size_t)k * 512 + (n - 512)];
            else if (n < 1152) v = Wc[(size_t)k * 128 + (n - 1024)];
            else               v = Wres[(size_t)k * 128 + (n - 1152)];
            Wt[idx] = f2bf(v);
        } else {
            int j = idx - NCAT * 256;
            if (j < 7 * 128 * 128) {
                int k = j >> 14, o = (j >> 7) & 127, i = j & 127;
                Wt2[j] = f2bf(Wconv[((size_t)o * 128 + i) * 7 + k]);
            }
        }
    } else {
        int e = (b - g2) * 256 + threadIdx.x;
        if (e < E) atomicAdd(&counts[ei[E + e]], 1);
    }
}

// ---------------- MFMA GEMM, BK=64, global_load_lds + XOR swizzle ----------------
// xl block (bcol<512) quantized to uint8 with per-(row,head) scale; others bf16
__global__ __launch_bounds__(256) void mfma_gemm(
    const ushort_t* __restrict__ A,   // [M][256] bf16
    const ushort_t* __restrict__ Wt,  // [1280][256] bf16
    uchar_t* __restrict__ xl8t, float* __restrict__ scales,
    ushort_t* __restrict__ xrb, ushort_t* __restrict__ xcb,
    ushort_t* __restrict__ resb, int M) {
    __shared__ __align__(1024) ushort_t As[128 * 64];
    __shared__ __align__(1024) ushort_t Bs[128 * 64];
    __shared__ float smax[128][2];
    int tid = threadIdx.x;
    int lane = tid & 63, wid = tid >> 6;
    int wr = (wid >> 1) * 64, wc = (wid & 1) * 64;
    int brow = blockIdx.y * 128, bcol = blockIdx.x * 128;
    int srow = lane >> 3;
    int sslot = lane & 7;
    int rl = lane & 15, kq = lane >> 4;
    f32x4 acc[4][4] = {};
    for (int k0 = 0; k0 < 256; k0 += 64) {
        #pragma unroll
        for (int j = 0; j < 4; ++j) {
            int r = (wid * 4 + j) * 8 + srow;
            int sl = sslot ^ (r & 7);
            gload16(A  + (size_t)(brow + r) * 256 + k0 + sl * 8,
                    (char*)As + (wid * 4 + j) * 1024);
            gload16(Wt + (size_t)(bcol + r) * 256 + k0 + sl * 8,
                    (char*)Bs + (wid * 4 + j) * 1024);
        }
        __syncthreads();
        #pragma unroll
        for (int ks = 0; ks < 2; ++ks) {
            int cb = ks * 64 + kq * 16;
            bf16x8 af[4], bfv[4];
            #pragma unroll
            for (int m = 0; m < 4; ++m) {
                int r = wr + m * 16 + rl;
                af[m] = *(const bf16x8*)((const char*)As + r * 128 + (cb ^ ((r & 7) << 4)));
            }
            #pragma unroll
            for (int n = 0; n < 4; ++n) {
                int r = wc + n * 16 + rl;
                bfv[n] = *(const bf16x8*)((const char*)Bs + r * 128 + (cb ^ ((r & 7) << 4)));
            }
            #pragma unroll
            for (int m = 0; m < 4; ++m)
                #pragma unroll
                for (int n = 0; n < 4; ++n)
                    acc[m][n] = __builtin_amdgcn_mfma_f32_16x16x32_bf16(
                        af[m], bfv[n], acc[m][n], 0, 0, 0);
        }
        __syncthreads();
    }
    int rowb = kq * 4;
    if (bcol < 512) {
        // ---- int8 quantized xl output with per-(row,head) scale ----
        int head = bcol >> 7;
        float rmax[4][4];
        #pragma unroll
        for (int m = 0; m < 4; ++m)
            #pragma unroll
            for (int q = 0; q < 4; ++q) {
                float t = fabsf(acc[m][0][q]);
                t = fmaxf(t, fabsf(acc[m][1][q]));
                t = fmaxf(t, fabsf(acc[m][2][q]));
                t = fmaxf(t, fabsf(acc[m][3][q]));
                #pragma unroll
                for (int o = 1; o < 16; o <<= 1) t = fmaxf(t, __shfl_xor(t, o));
                rmax[m][q] = t;
            }
        if (rl == 0) {
            #pragma unroll
            for (int m = 0; m < 4; ++m)
                #pragma unroll
                for (int q = 0; q < 4; ++q)
                    smax[wr + m * 16 + rowb + q][wid & 1] = rmax[m][q];
        }
        __syncthreads();
        #pragma unroll
        for (int m = 0; m < 4; ++m)
            #pragma unroll
            for (int q = 0; q < 4; ++q) {
                int row = wr + m * 16 + rowb + q;
                float sm = fmaxf(fmaxf(smax[row][0], smax[row][1]), 1e-8f);
                float s = sm * (1.f / 127.f);
                float rs = 127.f / sm;
                if ((wid & 1) == 0 && rl == 0)
                    scales[(size_t)(brow + row) * 4 + head] = s;
                #pragma unroll
                for (int n = 0; n < 4; ++n) {
                    int col = bcol + wc + n * 16 + rl;
                    int qv = (int)rintf(acc[m][n][q] * rs) + 128;
                    xl8t[(size_t)(brow + row) * 512 + col] = (uchar_t)qv;
                }
            }
        return;
    }
    ushort_t* dstp; int cstride, cb2;
    if (bcol < 1024)      { dstp = xrb;  cstride = 512; cb2 = bcol - 512; }
    else if (bcol < 1152) { dstp = xcb;  cstride = 128; cb2 = bcol - 1024; }
    else                  { dstp = resb; cstride = 128; cb2 = bcol - 1152; }
    #pragma unroll
    for (int m = 0; m < 4; ++m)
        #pragma unroll
        for (int n = 0; n < 4; ++n) {
            int col = cb2 + wc + n * 16 + rl;
            #pragma unroll
            for (int q = 0; q < 4; ++q) {
                int row = brow + wr + m * 16 + rowb + q;
                dstp[(size_t)row * cstride + col] = f2bf(acc[m][n][q]);
            }
        }
}

// ---------------- CSR build ----------------
__global__ __launch_bounds__(1024) void scan_kernel(
    const int* __restrict__ counts, int* __restrict__ offs,
    int* __restrict__ cursor, int N) {
    __shared__ int wsum[16];
    int t = threadIdx.x;
    int lane = t & 63, w = t >> 6;
    int base = t * 16;
    int local[16], s = 0;
    #pragma unroll
    for (int i = 0; i < 16; ++i) {
        int v = (base + i < N) ? counts[base + i] : 0;
        local[i] = v; s += v;
    }
    int sc = s;
    #pragma unroll
    for (int off = 1; off < 64; off <<= 1) {
        int v = __shfl_up(sc, off);
        if (lane >= off) sc += v;
    }
    if (lane == 63) wsum[w] = sc;
    __syncthreads();
    if (w == 0 && lane < 16) {
        int v = wsum[lane];
        int scv = v;
        #pragma unroll
        for (int off = 1; off < 16; off <<= 1) {
            int u = __shfl_up(scv, off);
            if (lane >= off) scv += u;
        }
        wsum[lane] = scv - v;
    }
    __syncthreads();
    int run = wsum[w] + sc - s;
    #pragma unroll
    for (int i = 0; i < 16; ++i) {
        if (base + i < N) { offs[base + i] = run; cursor[base + i] = run; }
        run += local[i];
    }
}

__global__ __launch_bounds__(256) void scatter_kernel(
    const int* __restrict__ ei, int* __restrict__ cursor,
    int* __restrict__ srcs, int E) {
    int e = blockIdx.x * 256 + threadIdx.x;
    if (e < E) {
        int d = ei[E + e];
        int p = atomicAdd(&cursor[d], 1);
        srcs[p] = ei[e];
    }
}

// ---------------- MFMA conv1d + relu + LN(cnn) -> hcn_ln (bf16) ----------------
__global__ __launch_bounds__(256) void conv_ln_kernel(
    const ushort_t* __restrict__ xcb, const float* __restrict__ cnn_b,
    const ushort_t* __restrict__ Wt2, const float* __restrict__ conv_b,
    const float* __restrict__ cnn_gamma, const float* __restrict__ cnn_beta,
    ushort_t* __restrict__ hcn_ln) {
    __shared__ ushort_t As[38][136];
    __shared__ __align__(1024) ushort_t Bs[128 * 128];
    __shared__ float hbuf[32][129];
    int tid = threadIdx.x;
    int lane = tid & 63, wid = tid >> 6;
    int wr = (wid >> 1) * 16, wc = (wid & 1) * 64;
    int b = blockIdx.y, l0 = blockIdx.x * 32;
    for (int u = tid; u < 38 * 16; u += 256) {
        int r = u >> 4, seg = u & 15;
        int l = l0 - 3 + r;
        uint4 o4 = make_uint4(0, 0, 0, 0);
        if (l >= 0 && l < 512) {
            uint4 v = *(const uint4*)(xcb + (size_t)(b * 512 + l) * 128 + seg * 8);
            float4 b0 = *(const float4*)(cnn_b + seg * 8);
            float4 b1 = *(const float4*)(cnn_b + seg * 8 + 4);
            o4.x = f2bf(bflo(v.x) + b0.x) | ((unsigned)f2bf(bfhi(v.x) + b0.y) << 16);
            o4.y = f2bf(bflo(v.y) + b0.z) | ((unsigned)f2bf(bfhi(v.y) + b0.w) << 16);
            o4.z = f2bf(bflo(v.z) + b1.x) | ((unsigned)f2bf(bfhi(v.z) + b1.y) << 16);
            o4.w = f2bf(bflo(v.w) + b1.z) | ((unsigned)f2bf(bfhi(v.w) + b1.w) << 16);
        }
        *(uint4*)&As[r][seg * 8] = o4;
    }
    f32x4 acc[4] = {};
    int rl = lane & 15, kb = (lane >> 4) * 8;
    int sr4 = lane >> 4, ss = lane & 15;
    for (int k = 0; k < 7; ++k) {
        __syncthreads();
        #pragma unroll
        for (int j = 0; j < 8; ++j) {
            int r = (wid * 8 + j) * 4 + sr4;
            int sl = ss ^ (r & 15);
            gload16(Wt2 + ((size_t)(k * 128 + r)) * 128 + sl * 8,
                    (char*)Bs + (wid * 8 + j) * 1024);
        }
        __syncthreads();
        #pragma unroll
        for (int kk = 0; kk < 4; ++kk) {
            bf16x8 af = *(const bf16x8*)&As[wr + rl + k][kk * 32 + kb];
            int cbyte = kk * 64 + (lane >> 4) * 16;
            #pragma unroll
            for (int n = 0; n < 4; ++n) {
                int r = wc + n * 16 + rl;
                bf16x8 bfr = *(const bf16x8*)((const char*)Bs + r * 256
                                              + (cbyte ^ ((r & 15) << 4)));
                acc[n] = __builtin_amdgcn_mfma_f32_16x16x32_bf16(af, bfr, acc[n], 0, 0, 0);
            }
        }
    }
    __syncthreads();
    int rowb = (lane >> 4) * 4;
    #pragma unroll
    for (int n = 0; n < 4; ++n) {
        int col = wc + n * 16 + rl;
        float cb = conv_b[col];
        #pragma unroll
        for (int q = 0; q < 4; ++q) {
            int r = wr + rowb + q;
            hbuf[r][col] = fmaxf(acc[n][q] + cb, 0.f);
        }
    }
    __syncthreads();
    for (int r = wid * 8; r < wid * 8 + 8; ++r) {
        int grow = b * 512 + l0 + r;
        float h0 = hbuf[r][lane], h1 = hbuf[r][lane + 64];
        float s = h0 + h1;
        #pragma unroll
        for (int off = 32; off; off >>= 1) s += __shfl_xor(s, off);
        float mu = s * (1.f / 128.f);
        float d0 = h0 - mu, d1 = h1 - mu;
        float vs = d0 * d0 + d1 * d1;
        #pragma unroll
        for (int off = 32; off; off >>= 1) vs += __shfl_xor(vs, off);
        float inv = rsqrtf(vs * (1.f / 128.f) + 1e-5f);
        size_t base = (size_t)grow * 128;
        hcn_ln[base + lane]      = f2bf(d0 * inv * cnn_gamma[lane]      + cnn_beta[lane]);
        hcn_ln[base + lane + 64] = f2bf(d1 * inv * cnn_gamma[lane + 64] + cnn_beta[lane + 64]);
    }
}

// ---------------- fused GAT (int8 gather, 2 waves/node) + final fuse/LN -> out ----------------
// block = 4 waves = 2 dst nodes x 2 half-edge-lists; LDS combine, even wave does epilogue
__global__ __launch_bounds__(256) void gat_final_kernel(
    const uchar_t* __restrict__ xl8t, const float* __restrict__ scales,
    const ushort_t* __restrict__ xrb,
    const int* __restrict__ srcs, const int* __restrict__ offs,
    const float* __restrict__ att, const float* __restrict__ gat_bias,
    const float* __restrict__ gat_gamma, const float* __restrict__ gat_beta,
    const ushort_t* __restrict__ hcn_ln, const ushort_t* __restrict__ resb,
    const float* __restrict__ res_b,
    const float* __restrict__ fuse_gamma, const float* __restrict__ fuse_beta,
    float* __restrict__ out, int E, int N) {
    __shared__ float comb[2][10][64];
    int tid = threadIdx.x;
    int lane = tid & 63, wid = tid >> 6;
    int pair = wid >> 1, half = wid & 1;
    int d = blockIdx.x * 2 + pair;
    int h = lane >> 4;
    const uint4 rv = ((const uint4*)(xrb + (size_t)d * HF))[lane];
    float xr8[8];
    xr8[0] = bflo(rv.x); xr8[1] = bfhi(rv.x);
    xr8[2] = bflo(rv.y); xr8[3] = bfhi(rv.y);
    xr8[4] = bflo(rv.z); xr8[5] = bfhi(rv.z);
    xr8[6] = bflo(rv.w); xr8[7] = bfhi(rv.w);
    const float LOG2E = 1.44269504f;
    const float4 a0 = ((const float4*)att)[lane * 2];
    const float4 a1 = ((const float4*)att)[lane * 2 + 1];
    const float aw[8] = {a0.x * LOG2E, a0.y * LOG2E, a0.z * LOG2E, a0.w * LOG2E,
                         a1.x * LOG2E, a1.y * LOG2E, a1.z * LOG2E, a1.w * LOG2E};
    float acc[8] = {};
    float dn = 0.f, sumexs = 0.f;

    // xl_j = sc*(q_j-128); leaky0.2(v)*a = a*(0.6v+0.4|v|)
    auto process = [&](uint2 lv, float sc) {
        float qf[8];
        qf[0] = (float)(lv.x & 0xff);         qf[1] = (float)((lv.x >> 8) & 0xff);
        qf[2] = (float)((lv.x >> 16) & 0xff); qf[3] = (float)(lv.x >> 24);
        qf[4] = (float)(lv.y & 0xff);         qf[5] = (float)((lv.y >> 8) & 0xff);
        qf[6] = (float)((lv.y >> 16) & 0xff); qf[7] = (float)(lv.y >> 24);
        float c = 128.f * sc;
        float s1 = 0.f, s2 = 0.f;
        #pragma unroll
        for (int j = 0; j < 8; ++j) {
            float v = fmaf(sc, qf[j], xr8[j]) - c;
            s1 = fmaf(v, aw[j], s1);
            s2 = fmaf(fabsf(v), aw[j], s2);
        }
        float s = fmaf(0.6f, s1, 0.4f * s2);
        s = rowsum16(s);
        float ex = exp2f(s);
        float exs = ex * sc;
        dn += ex; sumexs += exs;
        #pragma unroll
        for (int j = 0; j < 8; ++j) acc[j] = fmaf(exs, qf[j], acc[j]);
    };

    if (half == 0)
        process(((const uint2*)(xl8t + (size_t)d * 512))[lane],
                scales[(size_t)d * 4 + h]);   // self-loop

    int start = offs[d];
    int end = (d == N - 1) ? E : offs[d + 1];
    int mid = start + ((end - start) >> 1);
    int ps = half ? mid : start;
    int pe = half ? end : mid;
    int p = ps;
    for (; p + 3 < pe; p += 4) {
        int s0 = srcs[p], s1 = srcs[p + 1], s2 = srcs[p + 2], s3 = srcs[p + 3];
        uint2 l0 = ((const uint2*)(xl8t + (size_t)s0 * 512))[lane];
        uint2 l1 = ((const uint2*)(xl8t + (size_t)s1 * 512))[lane];
        uint2 l2 = ((const uint2*)(xl8t + (size_t)s2 * 512))[lane];
        uint2 l3 = ((const uint2*)(xl8t + (size_t)s3 * 512))[lane];
        float c0 = scales[(size_t)s0 * 4 + h];
        float c1 = scales[(size_t)s1 * 4 + h];
        float c2 = scales[(size_t)s2 * 4 + h];
        float c3 = scales[(size_t)s3 * 4 + h];
        process(l0, c0); process(l1, c1); process(l2, c2); process(l3, c3);
    }
    for (; p < pe; ++p) {
        int sp = srcs[p];
        process(((const uint2*)(xl8t + (size_t)sp * 512))[lane],
                scales[(size_t)sp * 4 + h]);
    }

    // combine the two half-waves via LDS
    if (half == 1) {
        #pragma unroll
        for (int j = 0; j < 8; ++j) comb[pair][j][lane] = acc[j];
        comb[pair][8][lane] = dn;
        comb[pair][9][lane] = sumexs;
    }
    __syncthreads();
    if (half == 1) return;
    #pragma unroll
    for (int j = 0; j < 8; ++j) acc[j] += comb[pair][j][lane];
    dn += comb[pair][8][lane];
    sumexs += comb[pair][9][lane];

    float inv = 1.f / dn;
    float corr = 128.f * sumexs;
    float v[8];
    #pragma unroll
    for (int j = 0; j < 8; ++j) {
        float t2 = (acc[j] - corr) * inv;
        t2 += __shfl_xor(t2, 16);
        t2 += __shfl_xor(t2, 32);
        v[j] = t2;
    }
    int col = (lane & 15) * 8 + 2 * h;
    float g0 = 0.25f * v[2 * h]     + gat_bias[col];
    float g1 = 0.25f * v[2 * h + 1] + gat_bias[col + 1];
    g0 = g0 > 0.f ? g0 : 0.01f * g0;
    g1 = g1 > 0.f ? g1 : 0.01f * g1;
    // LN(gat)
    float s = g0 + g1;
    #pragma unroll
    for (int off = 32; off; off >>= 1) s += __shfl_xor(s, off);
    float mu = s * (1.f / 128.f);
    float d0 = g0 - mu, d1 = g1 - mu;
    float vs = d0 * d0 + d1 * d1;
    #pragma unroll
    for (int off = 32; off; off >>= 1) vs += __shfl_xor(vs, off);
    float rinv = rsqrtf(vs * (1.f / 128.f) + 1e-5f);
    float hg0 = d0 * rinv * gat_gamma[col]     + gat_beta[col];
    float hg1 = d1 * rinv * gat_gamma[col + 1] + gat_beta[col + 1];
    // fuse: + hcn_ln + res + res_b, then LN(fuse)
    size_t base = (size_t)d * 128 + col;
    unsigned hcu = *(const unsigned*)(hcn_ln + base);
    unsigned rsu = *(const unsigned*)(resb + base);
    float v0 = hg0 + bflo(hcu) + bflo(rsu) + res_b[col];
    float v1 = hg1 + bfhi(hcu) + bfhi(rsu) + res_b[col + 1];
    s = v0 + v1;
    #pragma unroll
    for (int off = 32; off; off >>= 1) s += __shfl_xor(s, off);
    mu = s * (1.f / 128.f);
    d0 = v0 - mu; d1 = v1 - mu;
    vs = d0 * d0 + d1 * d1;
    #pragma unroll
    for (int off = 32; off; off >>= 1) vs += __shfl_xor(vs, off);
    rinv = rsqrtf(vs * (1.f / 128.f) + 1e-5f);
    float2 o2 = make_float2(d0 * rinv * fuse_gamma[col]     + fuse_beta[col],
                            d1 * rinv * fuse_gamma[col + 1] + fuse_beta[col + 1]);
    *(float2*)(out + base) = o2;
}

extern "C" void kernel_launch(void* const* d_in, const int* in_sizes, int n_in,
                              void* d_out, int out_size, void* d_ws, size_t ws_size,
                              hipStream_t stream) {
    const float* x         = (const float*)d_in[0];
    const int*   ei        = (const int*)d_in[1];
    const float* W_l       = (const float*)d_in[2];
    const float* W_r       = (const float*)d_in[3];
    const float* att       = (const float*)d_in[4];
    const float* gat_bias  = (const float*)d_in[5];
    const float* gat_gamma = (const float*)d_in[6];
    const float* gat_beta  = (const float*)d_in[7];
    const float* cnn_W     = (const float*)d_in[8];
    const float* cnn_b     = (const float*)d_in[9];
    const float* conv_W    = (const float*)d_in[10];
    const float* conv_b    = (const float*)d_in[11];
    const float* cnn_gamma = (const float*)d_in[12];
    const float* cnn_beta  = (const float*)d_in[13];
    const float* res_W     = (const float*)d_in[14];
    const float* res_b     = (const float*)d_in[15];
    const float* fuse_gamma= (const float*)d_in[16];
    const float* fuse_beta = (const float*)d_in[17];

    int N = in_sizes[0] / IN_F;   // 16384
    int E = in_sizes[1] / 2;      // 262144

    char* ws = (char*)d_ws;
    size_t off = 0;
    ushort_t* xb     = (ushort_t*)(ws + off); off += (size_t)N * IN_F * 2;
    ushort_t* Wt     = (ushort_t*)(ws + off); off += (size_t)NCAT * IN_F * 2;
    ushort_t* Wt2    = (ushort_t*)(ws + off); off += (size_t)7 * 128 * 128 * 2;
    uchar_t*  xl8t   = (uchar_t*)(ws + off);  off += (size_t)N * HF;        // 8MB int8
    float*    scales = (float*)(ws + off);    off += (size_t)N * 4 * 4;     // 256KB
    ushort_t* xrb    = (ushort_t*)(ws + off); off += (size_t)N * HF * 2;    // 16MB
    ushort_t* xcb    = (ushort_t*)(ws + off); off += (size_t)N * 128 * 2;
    ushort_t* resb   = (ushort_t*)(ws + off); off += (size_t)N * 128 * 2;
    ushort_t* hcn_ln = (ushort_t*)(ws + off); off += (size_t)N * 128 * 2;
    int*  counts     = (int*)(ws + off);  off += (size_t)N * 4;
    int*  offs       = (int*)(ws + off);  off += (size_t)N * 4;
    int*  cursor     = (int*)(ws + off);  off += (size_t)N * 4;
    int*  srcs       = (int*)(ws + off);  off += (size_t)E * 4;

    hipMemsetAsync(counts, 0, (size_t)N * 4, stream);

    dim3 blk(256);
    int n_cvt = N * IN_F;
    int g1 = (n_cvt / 8 + 255) / 256;
    int g2 = g1 + (NCAT * 256 + 7 * 128 * 128 + 255) / 256;
    int g3 = g2 + (E + 255) / 256;
    prep_kernel<<<g3, blk, 0, stream>>>(x, xb, n_cvt,
        W_l, W_r, cnn_W, res_W, conv_W, Wt, Wt2, ei, counts, E, g1, g2);

    scan_kernel<<<1, 1024, 0, stream>>>(counts, offs, cursor, N);
    scatter_kernel<<<(E + 255) / 256, blk, 0, stream>>>(ei, cursor, srcs, E);

    mfma_gemm<<<dim3(NCAT / 128, N / 128), blk, 0, stream>>>(
        xb, Wt, xl8t, scales, xrb, xcb, resb, N);

    conv_ln_kernel<<<dim3(16, 32), blk, 0, stream>>>(
        xcb, cnn_b, Wt2, conv_b, cnn_gamma, cnn_beta, hcn_ln);

    gat_final_kernel<<<N / 2, blk, 0, stream>>>(
        xl8t, scales, xrb, srcs, offs, att, gat_bias, gat_gamma, gat_beta,
        hcn_ln, resb, res_b, fuse_gamma, fuse_beta, (float*)d_out, E, N);
}

// Round 13
// 139.484 us; speedup vs baseline: 1.1003x; 1.1003x over previous
//
#include <hip/hip_runtime.h>
#include <hip/hip_bf16.h>
#include <math.h>

#define IN_F 256
#define OUT_F 128
#define HEADS 4
#define HF 512    // HEADS*OUT_F
#define NCAT 1280 // 512 + 512 + 128 + 128

typedef __hip_bfloat16 bf16;
typedef unsigned short ushort_t;
typedef unsigned char uchar_t;

using bf16x8 = __attribute__((ext_vector_type(8))) short;
using f32x4  = __attribute__((ext_vector_type(4))) float;

__device__ __forceinline__ float bflo(unsigned u) { return __uint_as_float(u << 16); }
__device__ __forceinline__ float bfhi(unsigned u) { return __uint_as_float(u & 0xffff0000u); }
__device__ __forceinline__ float bf2f(ushort_t u) { return __uint_as_float((unsigned)u << 16); }
__device__ __forceinline__ ushort_t f2bf(float f) {
    __hip_bfloat16 h = __float2bfloat16(f);
    return *reinterpret_cast<ushort_t*>(&h);
}

// async global->LDS, 16B per lane; dest = wave-uniform base + lane*16
__device__ __forceinline__ void gload16(const void* g, void* l) {
    __builtin_amdgcn_global_load_lds(
        (const __attribute__((address_space(1))) unsigned int*)g,
        (__attribute__((address_space(3))) unsigned int*)l, 16, 0, 0);
}

// sum over 16-lane row via DPP row_ror (all lanes end with full sum)
template <int CTRL>
__device__ __forceinline__ float dpp_add(float s) {
    int t = __builtin_amdgcn_update_dpp(0, __float_as_int(s), CTRL, 0xf, 0xf, true);
    return s + __int_as_float(t);
}
__device__ __forceinline__ float rowsum16(float s) {
    s = dpp_add<0x121>(s);
    s = dpp_add<0x122>(s);
    s = dpp_add<0x124>(s);
    s = dpp_add<0x128>(s);
    return s;
}

// ---------------- fused prep: cvt_x | build weights | hist ----------------
__global__ __launch_bounds__(256) void prep_kernel(
    const float* __restrict__ x, ushort_t* __restrict__ xb, int n_cvt,
    const float* __restrict__ Wl, const float* __restrict__ Wr,
    const float* __restrict__ Wc, const float* __restrict__ Wres,
    const float* __restrict__ Wconv,
    ushort_t* __restrict__ Wt, ushort_t* __restrict__ Wt2,
    const int* __restrict__ ei, int* __restrict__ counts, int E,
    int g1, int g2) {
    int b = blockIdx.x;
    if (b < g1) {
        int i = (b * 256 + threadIdx.x) * 8;
        if (i >= n_cvt) return;
        float4 a = *(const float4*)(x + i);
        float4 c = *(const float4*)(x + i + 4);
        uint4 o;
        o.x = f2bf(a.x) | ((unsigned)f2bf(a.y) << 16);
        o.y = f2bf(a.z) | ((unsigned)f2bf(a.w) << 16);
        o.z = f2bf(c.x) | ((unsigned)f2bf(c.y) << 16);
        o.w = f2bf(c.z) | ((unsigned)f2bf(c.w) << 16);
        *(uint4*)(xb + i) = o;
    } else if (b < g2) {
        int idx = (b - g1) * 256 + threadIdx.x;
        if (idx < NCAT * 256) {
            int n = idx >> 8, k = idx & 255;
            float v;
            if (n < 512)       v = Wl[(size_t)k * 512 + n];
            else if (n < 1024) v = Wr[(size_t)k * 512 + (n - 512)];
            else if (n < 1152) v = Wc[(size_t)k * 128 + (n - 1024)];
            else               v = Wres[(size_t)k * 128 + (n - 1152)];
            Wt[idx] = f2bf(v);
        } else {
            int j = idx - NCAT * 256;
            if (j < 7 * 128 * 128) {
                int k = j >> 14, o = (j >> 7) & 127, i = j & 127;
                Wt2[j] = f2bf(Wconv[((size_t)o * 128 + i) * 7 + k]);
            }
        }
    } else {
        int e = (b - g2) * 256 + threadIdx.x;
        if (e < E) atomicAdd(&counts[ei[E + e]], 1);
    }
}

// ---------------- merged: CSR scatter blocks + MFMA GEMM blocks ----------------
// blocks [0, SB): scatter; blocks [SB, SB+1280): gemm (bx = NCAT/128 cols)
__global__ __launch_bounds__(256) void gemm_scatter_kernel(
    const ushort_t* __restrict__ A,   // [M][256] bf16
    const ushort_t* __restrict__ Wt,  // [1280][256] bf16
    uchar_t* __restrict__ xl8t, float* __restrict__ scales,
    ushort_t* __restrict__ xrb, ushort_t* __restrict__ xcb,
    ushort_t* __restrict__ resb,
    const int* __restrict__ ei, int* __restrict__ cursor,
    int* __restrict__ srcs, int E, int SB) {
    __shared__ __align__(1024) ushort_t As[128 * 64];
    __shared__ __align__(1024) ushort_t Bs[128 * 64];
    __shared__ float smax[128][2];
    if (blockIdx.x < SB) {
        int e = blockIdx.x * 256 + threadIdx.x;
        if (e < E) {
            int dd = ei[E + e];
            int pp = atomicAdd(&cursor[dd], 1);
            srcs[pp] = ei[e];
        }
        return;
    }
    int bid = blockIdx.x - SB;
    int by = bid / 10, bx = bid - by * 10;
    int tid = threadIdx.x;
    int lane = tid & 63, wid = tid >> 6;
    int wr = (wid >> 1) * 64, wc = (wid & 1) * 64;
    int brow = by * 128, bcol = bx * 128;
    int srow = lane >> 3;
    int sslot = lane & 7;
    int rl = lane & 15, kq = lane >> 4;
    f32x4 acc[4][4] = {};
    for (int k0 = 0; k0 < 256; k0 += 64) {
        #pragma unroll
        for (int j = 0; j < 4; ++j) {
            int r = (wid * 4 + j) * 8 + srow;
            int sl = sslot ^ (r & 7);
            gload16(A  + (size_t)(brow + r) * 256 + k0 + sl * 8,
                    (char*)As + (wid * 4 + j) * 1024);
            gload16(Wt + (size_t)(bcol + r) * 256 + k0 + sl * 8,
                    (char*)Bs + (wid * 4 + j) * 1024);
        }
        __syncthreads();
        #pragma unroll
        for (int ks = 0; ks < 2; ++ks) {
            int cb = ks * 64 + kq * 16;
            bf16x8 af[4], bfv[4];
            #pragma unroll
            for (int m = 0; m < 4; ++m) {
                int r = wr + m * 16 + rl;
                af[m] = *(const bf16x8*)((const char*)As + r * 128 + (cb ^ ((r & 7) << 4)));
            }
            #pragma unroll
            for (int n = 0; n < 4; ++n) {
                int r = wc + n * 16 + rl;
                bfv[n] = *(const bf16x8*)((const char*)Bs + r * 128 + (cb ^ ((r & 7) << 4)));
            }
            #pragma unroll
            for (int m = 0; m < 4; ++m)
                #pragma unroll
                for (int n = 0; n < 4; ++n)
                    acc[m][n] = __builtin_amdgcn_mfma_f32_16x16x32_bf16(
                        af[m], bfv[n], acc[m][n], 0, 0, 0);
        }
        __syncthreads();
    }
    int rowb = kq * 4;
    if (bcol < 512) {
        // ---- int8 quantized xl output with per-(row,head) scale ----
        int head = bcol >> 7;
        float rmax[4][4];
        #pragma unroll
        for (int m = 0; m < 4; ++m)
            #pragma unroll
            for (int q = 0; q < 4; ++q) {
                float t = fabsf(acc[m][0][q]);
                t = fmaxf(t, fabsf(acc[m][1][q]));
                t = fmaxf(t, fabsf(acc[m][2][q]));
                t = fmaxf(t, fabsf(acc[m][3][q]));
                #pragma unroll
                for (int o = 1; o < 16; o <<= 1) t = fmaxf(t, __shfl_xor(t, o));
                rmax[m][q] = t;
            }
        if (rl == 0) {
            #pragma unroll
            for (int m = 0; m < 4; ++m)
                #pragma unroll
                for (int q = 0; q < 4; ++q)
                    smax[wr + m * 16 + rowb + q][wid & 1] = rmax[m][q];
        }
        __syncthreads();
        #pragma unroll
        for (int m = 0; m < 4; ++m)
            #pragma unroll
            for (int q = 0; q < 4; ++q) {
                int row = wr + m * 16 + rowb + q;
                float sm = fmaxf(fmaxf(smax[row][0], smax[row][1]), 1e-8f);
                float s = sm * (1.f / 127.f);
                float rs = 127.f / sm;
                if ((wid & 1) == 0 && rl == 0)
                    scales[(size_t)(brow + row) * 4 + head] = s;
                #pragma unroll
                for (int n = 0; n < 4; ++n) {
                    int col = bcol + wc + n * 16 + rl;
                    int qv = (int)rintf(acc[m][n][q] * rs) + 128;
                    xl8t[(size_t)(brow + row) * 512 + col] = (uchar_t)qv;
                }
            }
        return;
    }
    ushort_t* dstp; int cstride, cb2;
    if (bcol < 1024)      { dstp = xrb;  cstride = 512; cb2 = bcol - 512; }
    else if (bcol < 1152) { dstp = xcb;  cstride = 128; cb2 = bcol - 1024; }
    else                  { dstp = resb; cstride = 128; cb2 = bcol - 1152; }
    #pragma unroll
    for (int m = 0; m < 4; ++m)
        #pragma unroll
        for (int n = 0; n < 4; ++n) {
            int col = cb2 + wc + n * 16 + rl;
            #pragma unroll
            for (int q = 0; q < 4; ++q) {
                int row = brow + wr + m * 16 + rowb + q;
                dstp[(size_t)row * cstride + col] = f2bf(acc[m][n][q]);
            }
        }
}

// ---------------- CSR build ----------------
__global__ __launch_bounds__(1024) void scan_kernel(
    const int* __restrict__ counts, int* __restrict__ offs,
    int* __restrict__ cursor, int N) {
    __shared__ int wsum[16];
    int t = threadIdx.x;
    int lane = t & 63, w = t >> 6;
    int base = t * 16;
    int local[16], s = 0;
    #pragma unroll
    for (int i = 0; i < 16; ++i) {
        int v = (base + i < N) ? counts[base + i] : 0;
        local[i] = v; s += v;
    }
    int sc = s;
    #pragma unroll
    for (int off = 1; off < 64; off <<= 1) {
        int v = __shfl_up(sc, off);
        if (lane >= off) sc += v;
    }
    if (lane == 63) wsum[w] = sc;
    __syncthreads();
    if (w == 0 && lane < 16) {
        int v = wsum[lane];
        int scv = v;
        #pragma unroll
        for (int off = 1; off < 16; off <<= 1) {
            int u = __shfl_up(scv, off);
            if (lane >= off) scv += u;
        }
        wsum[lane] = scv - v;
    }
    __syncthreads();
    int run = wsum[w] + sc - s;
    #pragma unroll
    for (int i = 0; i < 16; ++i) {
        if (base + i < N) { offs[base + i] = run; cursor[base + i] = run; }
        run += local[i];
    }
}

// ---------------- MFMA conv1d + relu + LN(cnn) -> hcn_ln (bf16) ----------------
__global__ __launch_bounds__(256) void conv_ln_kernel(
    const ushort_t* __restrict__ xcb, const float* __restrict__ cnn_b,
    const ushort_t* __restrict__ Wt2, const float* __restrict__ conv_b,
    const float* __restrict__ cnn_gamma, const float* __restrict__ cnn_beta,
    ushort_t* __restrict__ hcn_ln) {
    __shared__ ushort_t As[38][136];
    __shared__ __align__(1024) ushort_t Bs[128 * 128];
    __shared__ float hbuf[32][129];
    int tid = threadIdx.x;
    int lane = tid & 63, wid = tid >> 6;
    int wr = (wid >> 1) * 16, wc = (wid & 1) * 64;
    int b = blockIdx.y, l0 = blockIdx.x * 32;
    for (int u = tid; u < 38 * 16; u += 256) {
        int r = u >> 4, seg = u & 15;
        int l = l0 - 3 + r;
        uint4 o4 = make_uint4(0, 0, 0, 0);
        if (l >= 0 && l < 512) {
            uint4 v = *(const uint4*)(xcb + (size_t)(b * 512 + l) * 128 + seg * 8);
            float4 b0 = *(const float4*)(cnn_b + seg * 8);
            float4 b1 = *(const float4*)(cnn_b + seg * 8 + 4);
            o4.x = f2bf(bflo(v.x) + b0.x) | ((unsigned)f2bf(bfhi(v.x) + b0.y) << 16);
            o4.y = f2bf(bflo(v.y) + b0.z) | ((unsigned)f2bf(bfhi(v.y) + b0.w) << 16);
            o4.z = f2bf(bflo(v.z) + b1.x) | ((unsigned)f2bf(bfhi(v.z) + b1.y) << 16);
            o4.w = f2bf(bflo(v.w) + b1.z) | ((unsigned)f2bf(bfhi(v.w) + b1.w) << 16);
        }
        *(uint4*)&As[r][seg * 8] = o4;
    }
    f32x4 acc[4] = {};
    int rl = lane & 15, kb = (lane >> 4) * 8;
    int sr4 = lane >> 4, ss = lane & 15;
    for (int k = 0; k < 7; ++k) {
        __syncthreads();
        #pragma unroll
        for (int j = 0; j < 8; ++j) {
            int r = (wid * 8 + j) * 4 + sr4;
            int sl = ss ^ (r & 15);
            gload16(Wt2 + ((size_t)(k * 128 + r)) * 128 + sl * 8,
                    (char*)Bs + (wid * 8 + j) * 1024);
        }
        __syncthreads();
        #pragma unroll
        for (int kk = 0; kk < 4; ++kk) {
            bf16x8 af = *(const bf16x8*)&As[wr + rl + k][kk * 32 + kb];
            int cbyte = kk * 64 + (lane >> 4) * 16;
            #pragma unroll
            for (int n = 0; n < 4; ++n) {
                int r = wc + n * 16 + rl;
                bf16x8 bfr = *(const bf16x8*)((const char*)Bs + r * 256
                                              + (cbyte ^ ((r & 15) << 4)));
                acc[n] = __builtin_amdgcn_mfma_f32_16x16x32_bf16(af, bfr, acc[n], 0, 0, 0);
            }
        }
    }
    __syncthreads();
    int rowb = (lane >> 4) * 4;
    #pragma unroll
    for (int n = 0; n < 4; ++n) {
        int col = wc + n * 16 + rl;
        float cb = conv_b[col];
        #pragma unroll
        for (int q = 0; q < 4; ++q) {
            int r = wr + rowb + q;
            hbuf[r][col] = fmaxf(acc[n][q] + cb, 0.f);
        }
    }
    __syncthreads();
    for (int r = wid * 8; r < wid * 8 + 8; ++r) {
        int grow = b * 512 + l0 + r;
        float h0 = hbuf[r][lane], h1 = hbuf[r][lane + 64];
        float s = h0 + h1;
        #pragma unroll
        for (int off = 32; off; off >>= 1) s += __shfl_xor(s, off);
        float mu = s * (1.f / 128.f);
        float d0 = h0 - mu, d1 = h1 - mu;
        float vs = d0 * d0 + d1 * d1;
        #pragma unroll
        for (int off = 32; off; off >>= 1) vs += __shfl_xor(vs, off);
        float inv = rsqrtf(vs * (1.f / 128.f) + 1e-5f);
        size_t base = (size_t)grow * 128;
        hcn_ln[base + lane]      = f2bf(d0 * inv * cnn_gamma[lane]      + cnn_beta[lane]);
        hcn_ln[base + lane + 64] = f2bf(d1 * inv * cnn_gamma[lane + 64] + cnn_beta[lane + 64]);
    }
}

// ---------------- fused GAT (int8 gather, pipelined) + final fuse/LN -> out ----------------
__global__ __launch_bounds__(256) void gat_final_kernel(
    const uchar_t* __restrict__ xl8t, const float* __restrict__ scales,
    const ushort_t* __restrict__ xrb,
    const int* __restrict__ srcs, const int* __restrict__ offs,
    const float* __restrict__ att, const float* __restrict__ gat_bias,
    const float* __restrict__ gat_gamma, const float* __restrict__ gat_beta,
    const ushort_t* __restrict__ hcn_ln, const ushort_t* __restrict__ resb,
    const float* __restrict__ res_b,
    const float* __restrict__ fuse_gamma, const float* __restrict__ fuse_beta,
    float* __restrict__ out, int E, int N) {
    int wid = (blockIdx.x * 256 + threadIdx.x) >> 6;
    int lane = threadIdx.x & 63;
    if (wid >= N) return;
    int d = wid;
    int h = lane >> 4;
    const uint4 rv = ((const uint4*)(xrb + (size_t)d * HF))[lane];
    float xr8[8];
    xr8[0] = bflo(rv.x); xr8[1] = bfhi(rv.x);
    xr8[2] = bflo(rv.y); xr8[3] = bfhi(rv.y);
    xr8[4] = bflo(rv.z); xr8[5] = bfhi(rv.z);
    xr8[6] = bflo(rv.w); xr8[7] = bfhi(rv.w);
    const float LOG2E = 1.44269504f;
    const float4 a0 = ((const float4*)att)[lane * 2];
    const float4 a1 = ((const float4*)att)[lane * 2 + 1];
    const float aw[8] = {a0.x * LOG2E, a0.y * LOG2E, a0.z * LOG2E, a0.w * LOG2E,
                         a1.x * LOG2E, a1.y * LOG2E, a1.z * LOG2E, a1.w * LOG2E};
    float acc[8] = {};
    float dn = 0.f, sumexs = 0.f;

    // xl_j = sc*(q_j-128); leaky0.2(v)*a = a*(0.6v+0.4|v|)
    auto process = [&](uint2 lv, float sc) {
        float qf[8];
        qf[0] = (float)(lv.x & 0xff);         qf[1] = (float)((lv.x >> 8) & 0xff);
        qf[2] = (float)((lv.x >> 16) & 0xff); qf[3] = (float)(lv.x >> 24);
        qf[4] = (float)(lv.y & 0xff);         qf[5] = (float)((lv.y >> 8) & 0xff);
        qf[6] = (float)((lv.y >> 16) & 0xff); qf[7] = (float)(lv.y >> 24);
        float c = 128.f * sc;
        float s1 = 0.f, s2 = 0.f;
        #pragma unroll
        for (int j = 0; j < 8; ++j) {
            float v = fmaf(sc, qf[j], xr8[j]) - c;
            s1 = fmaf(v, aw[j], s1);
            s2 = fmaf(fabsf(v), aw[j], s2);
        }
        float s = fmaf(0.6f, s1, 0.4f * s2);
        s = rowsum16(s);
        float ex = exp2f(s);
        float exs = ex * sc;
        dn += ex; sumexs += exs;
        #pragma unroll
        for (int j = 0; j < 8; ++j) acc[j] = fmaf(exs, qf[j], acc[j]);
    };

    process(((const uint2*)(xl8t + (size_t)d * 512))[lane],
            scales[(size_t)d * 4 + h]);   // self-loop

    int start = offs[d];
    int end = (d == N - 1) ? E : offs[d + 1];
    int nfull = (end - start) >> 2;
    int p = start;
    // software-pipelined batches: issue batch k+1 loads before processing batch k
    uint2 L0, L1, L2, L3;
    float C0, C1, C2, C3;
    if (nfull > 0) {
        int s0 = srcs[p], s1 = srcs[p + 1], s2 = srcs[p + 2], s3 = srcs[p + 3];
        L0 = ((const uint2*)(xl8t + (size_t)s0 * 512))[lane];
        L1 = ((const uint2*)(xl8t + (size_t)s1 * 512))[lane];
        L2 = ((const uint2*)(xl8t + (size_t)s2 * 512))[lane];
        L3 = ((const uint2*)(xl8t + (size_t)s3 * 512))[lane];
        C0 = scales[(size_t)s0 * 4 + h];
        C1 = scales[(size_t)s1 * 4 + h];
        C2 = scales[(size_t)s2 * 4 + h];
        C3 = scales[(size_t)s3 * 4 + h];
        p += 4;
    }
    for (int b = 1; b < nfull; ++b) {
        int s0 = srcs[p], s1 = srcs[p + 1], s2 = srcs[p + 2], s3 = srcs[p + 3];
        uint2 M0 = ((const uint2*)(xl8t + (size_t)s0 * 512))[lane];
        uint2 M1 = ((const uint2*)(xl8t + (size_t)s1 * 512))[lane];
        uint2 M2 = ((const uint2*)(xl8t + (size_t)s2 * 512))[lane];
        uint2 M3 = ((const uint2*)(xl8t + (size_t)s3 * 512))[lane];
        float D0 = scales[(size_t)s0 * 4 + h];
        float D1 = scales[(size_t)s1 * 4 + h];
        float D2 = scales[(size_t)s2 * 4 + h];
        float D3 = scales[(size_t)s3 * 4 + h];
        p += 4;
        process(L0, C0); process(L1, C1); process(L2, C2); process(L3, C3);
        L0 = M0; L1 = M1; L2 = M2; L3 = M3;
        C0 = D0; C1 = D1; C2 = D2; C3 = D3;
    }
    if (nfull > 0) {
        process(L0, C0); process(L1, C1); process(L2, C2); process(L3, C3);
    }
    for (; p < end; ++p) {
        int sp = srcs[p];
        process(((const uint2*)(xl8t + (size_t)sp * 512))[lane],
                scales[(size_t)sp * 4 + h]);
    }

    float inv = 1.f / dn;
    float corr = 128.f * sumexs;
    float v[8];
    #pragma unroll
    for (int j = 0; j < 8; ++j) {
        float t2 = (acc[j] - corr) * inv;
        t2 += __shfl_xor(t2, 16);
        t2 += __shfl_xor(t2, 32);
        v[j] = t2;
    }
    int col = (lane & 15) * 8 + 2 * h;
    float g0 = 0.25f * v[2 * h]     + gat_bias[col];
    float g1 = 0.25f * v[2 * h + 1] + gat_bias[col + 1];
    g0 = g0 > 0.f ? g0 : 0.01f * g0;
    g1 = g1 > 0.f ? g1 : 0.01f * g1;
    // LN(gat)
    float s = g0 + g1;
    #pragma unroll
    for (int off = 32; off; off >>= 1) s += __shfl_xor(s, off);
    float mu = s * (1.f / 128.f);
    float d0 = g0 - mu, d1 = g1 - mu;
    float vs = d0 * d0 + d1 * d1;
    #pragma unroll
    for (int off = 32; off; off >>= 1) vs += __shfl_xor(vs, off);
    float rinv = rsqrtf(vs * (1.f / 128.f) + 1e-5f);
    float hg0 = d0 * rinv * gat_gamma[col]     + gat_beta[col];
    float hg1 = d1 * rinv * gat_gamma[col + 1] + gat_beta[col + 1];
    // fuse: + hcn_ln + res + res_b, then LN(fuse)
    size_t base = (size_t)d * 128 + col;
    unsigned hcu = *(const unsigned*)(hcn_ln + base);
    unsigned rsu = *(const unsigned*)(resb + base);
    float v0 = hg0 + bflo(hcu) + bflo(rsu) + res_b[col];
    float v1 = hg1 + bfhi(hcu) + bfhi(rsu) + res_b[col + 1];
    s = v0 + v1;
    #pragma unroll
    for (int off = 32; off; off >>= 1) s += __shfl_xor(s, off);
    mu = s * (1.f / 128.f);
    d0 = v0 - mu; d1 = v1 - mu;
    vs = d0 * d0 + d1 * d1;
    #pragma unroll
    for (int off = 32; off; off >>= 1) vs += __shfl_xor(vs, off);
    rinv = rsqrtf(vs * (1.f / 128.f) + 1e-5f);
    float2 o2 = make_float2(d0 * rinv * fuse_gamma[col]     + fuse_beta[col],
                            d1 * rinv * fuse_gamma[col + 1] + fuse_beta[col + 1]);
    *(float2*)(out + base) = o2;
}

extern "C" void kernel_launch(void* const* d_in, const int* in_sizes, int n_in,
                              void* d_out, int out_size, void* d_ws, size_t ws_size,
                              hipStream_t stream) {
    const float* x         = (const float*)d_in[0];
    const int*   ei        = (const int*)d_in[1];
    const float* W_l       = (const float*)d_in[2];
    const float* W_r       = (const float*)d_in[3];
    const float* att       = (const float*)d_in[4];
    const float* gat_bias  = (const float*)d_in[5];
    const float* gat_gamma = (const float*)d_in[6];
    const float* gat_beta  = (const float*)d_in[7];
    const float* cnn_W     = (const float*)d_in[8];
    const float* cnn_b     = (const float*)d_in[9];
    const float* conv_W    = (const float*)d_in[10];
    const float* conv_b    = (const float*)d_in[11];
    const float* cnn_gamma = (const float*)d_in[12];
    const float* cnn_beta  = (const float*)d_in[13];
    const float* res_W     = (const float*)d_in[14];
    const float* res_b     = (const float*)d_in[15];
    const float* fuse_gamma= (const float*)d_in[16];
    const float* fuse_beta = (const float*)d_in[17];

    int N = in_sizes[0] / IN_F;   // 16384
    int E = in_sizes[1] / 2;      // 262144

    char* ws = (char*)d_ws;
    size_t off = 0;
    ushort_t* xb     = (ushort_t*)(ws + off); off += (size_t)N * IN_F * 2;
    ushort_t* Wt     = (ushort_t*)(ws + off); off += (size_t)NCAT * IN_F * 2;
    ushort_t* Wt2    = (ushort_t*)(ws + off); off += (size_t)7 * 128 * 128 * 2;
    uchar_t*  xl8t   = (uchar_t*)(ws + off);  off += (size_t)N * HF;        // 8MB int8
    float*    scales = (float*)(ws + off);    off += (size_t)N * 4 * 4;     // 256KB
    ushort_t* xrb    = (ushort_t*)(ws + off); off += (size_t)N * HF * 2;    // 16MB
    ushort_t* xcb    = (ushort_t*)(ws + off); off += (size_t)N * 128 * 2;
    ushort_t* resb   = (ushort_t*)(ws + off); off += (size_t)N * 128 * 2;
    ushort_t* hcn_ln = (ushort_t*)(ws + off); off += (size_t)N * 128 * 2;
    int*  counts     = (int*)(ws + off);  off += (size_t)N * 4;
    int*  offs       = (int*)(ws + off);  off += (size_t)N * 4;
    int*  cursor     = (int*)(ws + off);  off += (size_t)N * 4;
    int*  srcs       = (int*)(ws + off);  off += (size_t)E * 4;

    hipMemsetAsync(counts, 0, (size_t)N * 4, stream);

    dim3 blk(256);
    int n_cvt = N * IN_F;
    int g1 = (n_cvt / 8 + 255) / 256;
    int g2 = g1 + (NCAT * 256 + 7 * 128 * 128 + 255) / 256;
    int g3 = g2 + (E + 255) / 256;
    prep_kernel<<<g3, blk, 0, stream>>>(x, xb, n_cvt,
        W_l, W_r, cnn_W, res_W, conv_W, Wt, Wt2, ei, counts, E, g1, g2);

    scan_kernel<<<1, 1024, 0, stream>>>(counts, offs, cursor, N);

    // merged scatter (SB blocks) + gemm (1280 blocks): scatter overlaps gemm
    int SB = (E + 255) / 256;
    gemm_scatter_kernel<<<SB + (NCAT / 128) * (N / 128), blk, 0, stream>>>(
        xb, Wt, xl8t, scales, xrb, xcb, resb, ei, cursor, srcs, E, SB);

    conv_ln_kernel<<<dim3(16, 32), blk, 0, stream>>>(
        xcb, cnn_b, Wt2, conv_b, cnn_gamma, cnn_beta, hcn_ln);

    gat_final_kernel<<<(N + 3) / 4, blk, 0, stream>>>(
        xl8t, scales, xrb, srcs, offs, att, gat_bias, gat_gamma, gat_beta,
        hcn_ln, resb, res_b, fuse_gamma, fuse_beta, (float*)d_out, E, N);
}